// Round 7
// baseline (555.646 us; speedup 1.0000x reference)
//
#include <hip/hip_runtime.h>
#include <hip/hip_bf16.h>

#define B_ 8
#define N_ 2048
#define D_ 256

using bf16 = __hip_bfloat16;
typedef short v8s __attribute__((ext_vector_type(8)));
typedef float v4f __attribute__((ext_vector_type(4)));
typedef float v16f __attribute__((ext_vector_type(16)));
typedef unsigned int u32;

__device__ __forceinline__ v4f mfma16(v8s a, v8s b, v4f c) {
  return __builtin_amdgcn_mfma_f32_16x16x32_bf16(a, b, c, 0, 0, 0);
}
__device__ __forceinline__ v16f mfma32(v8s a, v8s b, v16f c) {
  return __builtin_amdgcn_mfma_f32_32x32x16_bf16(a, b, c, 0, 0, 0);
}
__device__ __forceinline__ v8s ldb8(const bf16* p) {
  return *reinterpret_cast<const v8s*>(p);
}
__device__ __forceinline__ void glds16(const void* g, void* l) {
  __builtin_amdgcn_global_load_lds((const __attribute__((address_space(1))) u32*)g,
                                   (__attribute__((address_space(3))) u32*)l, 16, 0, 0);
}
__device__ __forceinline__ unsigned short f2bu(float f) {
  bf16 b = __float2bfloat16(f);
  return *reinterpret_cast<unsigned short*>(&b);
}
__device__ __forceinline__ float bs2f(short s) {
  union { u32 i; float f; } v; v.i = ((u32)(unsigned short)s) << 16; return v.f;
}
__device__ __forceinline__ float lo16(u32 u) { union {u32 i; float f;} v; v.i = u << 16; return v.f; }
__device__ __forceinline__ float hi16(u32 u) { union {u32 i; float f;} v; v.i = u & 0xffff0000u; return v.f; }
__device__ __forceinline__ u32 pack2(float a, float b) {
  return (u32)f2bu(a) | ((u32)f2bu(b) << 16);
}
__device__ __forceinline__ float fsigmoid(float x) { return 1.0f / (1.0f + __expf(-x)); }
__device__ __forceinline__ float ftanh(float x) {
  float ax = fabsf(x);
  float t = __expf(-2.0f * ax);
  float r = (1.0f - t) / (1.0f + t);
  return copysignf(r, x);
}

// ------- K0: merged casts: blocks 0..4095 -> x cast; 4096..8191 -> xt normalize -------
__global__ __launch_bounds__(256) void k_cast(const float* __restrict__ x,
                                              bf16* __restrict__ xb16,
                                              const float* __restrict__ xt,
                                              bf16* __restrict__ xtn) {
  int blk = blockIdx.x;
  if (blk < 4096) {
    int i = blk * 256 + threadIdx.x;
    float4 v = reinterpret_cast<const float4*>(x)[i];
    ushort4 o;
    o.x = f2bu(v.x); o.y = f2bu(v.y); o.z = f2bu(v.z); o.w = f2bu(v.w);
    reinterpret_cast<ushort4*>(xb16)[i] = o;
  } else {
    int i = (blk - 4096) * 256 + threadIdx.x;     // one wave per 256-elem row
    float4 v = reinterpret_cast<const float4*>(xt)[i];
    float s = v.x * v.x + v.y * v.y + v.z * v.z + v.w * v.w;
#pragma unroll
    for (int off = 32; off > 0; off >>= 1) s += __shfl_xor(s, off);
    float rinv = 1.0f / fmaxf(sqrtf(s), 1e-8f);
    ushort4 o;
    o.x = f2bu(v.x * rinv); o.y = f2bu(v.y * rinv);
    o.z = f2bu(v.z * rinv); o.w = f2bu(v.w * rinv);
    reinterpret_cast<ushort4*>(xtn)[i] = o;
  }
}

// ---------------- K0c: merged tiny prep (W transpose + Wih/Whh cast) ----------
__global__ __launch_bounds__(256) void k_prep(const float* __restrict__ W,
                                              bf16* __restrict__ Wt,
                                              const float* __restrict__ Wih,
                                              bf16* __restrict__ Wih16,
                                              const float* __restrict__ Whh,
                                              bf16* __restrict__ Whh16) {
  int blk = blockIdx.x;
  if (blk < 256) {                                 // W[d][h] -> Wt[h][d]
    int idx = blk * 256 + threadIdx.x;
    int d = idx >> 8, h = idx & 255;
    Wt[h * 256 + d] = __float2bfloat16(W[idx]);
  } else if (blk < 448) {                          // Wih cast (49152 x4)
    int i = (blk - 256) * 256 + threadIdx.x;
    float4 v = reinterpret_cast<const float4*>(Wih)[i];
    ushort4 o;
    o.x = f2bu(v.x); o.y = f2bu(v.y); o.z = f2bu(v.z); o.w = f2bu(v.w);
    reinterpret_cast<ushort4*>(Wih16)[i] = o;
  } else {                                         // Whh cast
    int i = (blk - 448) * 256 + threadIdx.x;
    float4 v = reinterpret_cast<const float4*>(Whh)[i];
    ushort4 o;
    o.x = f2bu(v.x); o.y = f2bu(v.y); o.z = f2bu(v.z); o.w = f2bu(v.w);
    reinterpret_cast<ushort4*>(Whh16)[i] = o;
  }
}

// ------- K1: bit-transposed mask: maskT[b][g32][col] bit r = adj[row g*32+r][col] -------
__global__ __launch_bounds__(256) void k_packT(const int* __restrict__ adj,
                                               u32* __restrict__ maskT) {
  int bi = blockIdx.x;                             // 1024 = 512 (b,g) x 2 halves
  int bg = bi >> 1, half = bi & 1;
  const int* base = adj + (size_t)bg * 32 * 2048;
  int c0 = half * 1024 + threadIdx.x * 4;
  u32 w0 = 0, w1 = 0, w2 = 0, w3 = 0;
#pragma unroll 4
  for (int r = 0; r < 32; r++) {
    int4 v = *reinterpret_cast<const int4*>(base + r * 2048 + c0);
    w0 |= (u32)(v.x > 0) << r;
    w1 |= (u32)(v.y > 0) << r;
    w2 |= (u32)(v.z > 0) << r;
    w3 |= (u32)(v.w > 0) << r;
  }
  uint4 o; o.x = w0; o.y = w1; o.z = w2; o.w = w3;
  *reinterpret_cast<uint4*>(maskT + (size_t)bg * 2048 + c0) = o;
}

// ---------------- K3: WhT[b][h][m] = sum_d Wt[h][d] * x16[b][m][d] ----------------
__global__ __launch_bounds__(256) void k_wht(const bf16* __restrict__ x,
                                             const bf16* __restrict__ Wt,
                                             bf16* __restrict__ WhT) {
  int wid = blockIdx.x * 4 + (threadIdx.x >> 6);   // 4096 waves
  int lane = threadIdx.x & 63, lr = lane & 15, quad = lane >> 4;
  int b = wid >> 9;
  int rem = wid & 511;
  int h0 = (rem >> 5) << 4;                        // 16 h-tiles
  int m0 = (rem & 31) << 6;                        // 32 m-strips of 64

  v8s a[8];
  const bf16* arow = Wt + (size_t)(h0 + lr) * D_ + quad * 8;
#pragma unroll
  for (int ks = 0; ks < 8; ks++) a[ks] = ldb8(arow + ks * 32);

  const bf16* xb = x + (size_t)b * N_ * D_;
#pragma unroll
  for (int mt = 0; mt < 4; mt++) {
    v4f acc = {0.f, 0.f, 0.f, 0.f};
    const bf16* brow = xb + (size_t)(m0 + mt * 16 + lr) * D_ + quad * 8;
#pragma unroll
    for (int ks = 0; ks < 8; ks++) acc = mfma16(a[ks], ldb8(brow + ks * 32), acc);
    bf16* o = WhT + ((size_t)b * D_ + h0 + quad * 4) * N_ + m0 + mt * 16 + lr;
#pragma unroll
    for (int r = 0; r < 4; r++) o[(size_t)r * N_] = __float2bfloat16(acc[r]);
  }
}

// ---------------- K4: fused attention v6 — single-buffer, 3 blocks/CU ----------
// block = 128 Q-rows (wave owns 32), m-split x8 (grid 1024 -> 3 resident/CU).
// Classic 2-barrier K-loop: barrier; glds stage; barrier(drain); compute.
// LDS 43 KB -> 3 blocks/CU (vs 74 KB dbuf -> 2). Pre-normalized xtn: QK = cos.
__global__ __launch_bounds__(256, 3) void k_attn(const bf16* __restrict__ xtn,
                                                 const u32* __restrict__ maskT,
                                                 const bf16* __restrict__ WhT,
                                                 bf16* __restrict__ po,
                                                 float* __restrict__ pls) {
  __shared__ __align__(16) bf16 xts[32 * 256];     // 16 KB, slot = g ^ (m&7)
  __shared__ __align__(16) bf16 whs[256 * 32];     // 16 KB, slot = g ^ ((h>>1)&3)
  __shared__ __align__(16) bf16 pbuf[4][32 * 40];  // pitch 80 B, 10 KB

  const int tid = threadIdx.x;
  const int w = tid >> 6, lane = tid & 63;
  const int l5 = lane >> 5, l31 = lane & 31;
  const int b = blockIdx.x & 7;                    // XCD-resident batch
  const int nt = (blockIdx.x >> 3) & 15;
  const int mh = blockIdx.x >> 7;                  // 8 m-splits of 256
  const int n0w = nt * 128 + w * 32;
  const int mbase = mh * 256;

  const bf16* xtb = xtn + (size_t)b * N_ * D_;
  const bf16* whb = WhT + (size_t)b * D_ * N_;

  // Q fragments: A-layout for 32x32x16 (row = l31, k = kt*16 + l5*8 + j)
  v8s q[16];
  {
    const bf16* qrow = xtb + (size_t)(n0w + l31) * D_ + l5 * 8;
#pragma unroll
    for (int kt = 0; kt < 16; kt++) q[kt] = ldb8(qrow + kt * 16);
  }
  // per-lane mask column pointer: bit r = Q-row n0w + r, col = mbase + ii*32 + l31
  const u32* mrow = maskT + ((size_t)(b * 64 + nt * 4 + w)) * 2048 + mbase + l31;

  auto stage = [&](int m0) {
    const char* gx = (const char*)(xtb + (size_t)m0 * D_);
    char* lx = ((char*)xts) + w * 4096;
#pragma unroll
    for (int j = 0; j < 4; j++) {
      int m = w * 8 + j * 2 + l5;
      int gg = l31 ^ (m & 7);
      glds16(gx + (size_t)m * 512 + gg * 16, lx + j * 1024);
    }
    char* lw = ((char*)whs) + w * 4096;
#pragma unroll
    for (int j = 0; j < 4; j++) {
      int h = w * 64 + j * 16 + (lane >> 2);
      int g = (lane & 3) ^ ((lane >> 3) & 3);      // slot = g ^ ((h>>1)&3)
      glds16((const char*)(whb + (size_t)h * N_ + m0) + g * 16, lw + j * 1024);
    }
  };

  v16f o[8];
#pragma unroll
  for (int t = 0; t < 8; t++) o[t] = (v16f)(0.f);
  float lsum = 0.f;

  u32 mword = mrow[0];

#pragma unroll 1
  for (int ii = 0; ii < 8; ii++) {
    __syncthreads();                       // prev iter's readers done
    stage(mbase + ii * 32);
    u32 mnext = (ii + 1 < 8) ? mrow[(ii + 1) * 32] : 0u;
    __syncthreads();                       // drain: staged data visible

    // QK: S(32q x 32m) = cos; K-frags from swizzled LDS
    v16f s = (v16f)(0.f);
    const bf16* xb = xts + l31 * 256;
#pragma unroll
    for (int kt = 0; kt < 16; kt++) {
      int g = ((kt * 2 + l5) ^ (l31 & 7)) * 8;
      s = mfma32(q[kt], ldb8(xb + g), s);
    }

    // exp + P staging (C-layout -> pbuf rows); bit per C-row from mword
    bf16* pb = pbuf[w];
#pragma unroll
    for (int j = 0; j < 16; j++) {
      int row = (j & 3) + 8 * (j >> 2) + 4 * l5;
      float p = ((mword >> row) & 1u) ? __expf(s[j]) : 0.f;
      pb[row * 40 + l31] = __float2bfloat16(p);
    }
    mword = mnext;

    // P A-fragments (pitch 80 B, 16B-aligned) + row-sum from the same frags
    v8s pa0 = ldb8(pb + l31 * 40 + l5 * 8);
    v8s pa1 = ldb8(pb + l31 * 40 + 16 + l5 * 8);
#pragma unroll
    for (int e = 0; e < 8; e++) lsum += bs2f(pa0[e]) + bs2f(pa1[e]);

    // PV: O(32q x 256h) += P(32x32) @ Wh(32x256)
#pragma unroll
    for (int ht = 0; ht < 8; ht++) {
      const bf16* wb = whs + (ht * 32 + l31) * 32;
      int s0 = (l5 ^ ((l31 >> 1) & 3)) * 8;
      int s1 = ((2 + l5) ^ ((l31 >> 1) & 3)) * 8;
      o[ht] = mfma32(pa0, ldb8(wb + s0), o[ht]);
      o[ht] = mfma32(pa1, ldb8(wb + s1), o[ht]);
    }
  }

  // partial row-sums: combine the two k-halves; lanes 0..31 hold rows 0..31
  lsum += __shfl_xor(lsum, 32);
  if (lane < 32) pls[(size_t)mh * (B_ * N_) + b * N_ + n0w + l31] = lsum;

  // partial O store (C-layout scatter, bf16)
  bf16* pob = po + (size_t)mh * ((size_t)B_ * N_ * D_) + ((size_t)b * N_ + n0w) * D_;
#pragma unroll
  for (int ht = 0; ht < 8; ht++) {
#pragma unroll
    for (int j = 0; j < 16; j++) {
      int row = (j & 3) + 8 * (j >> 2) + 4 * l5;
      pob[(size_t)row * D_ + ht * 32 + l31] = __float2bfloat16(o[ht][j]);
    }
  }
}

// ---------------- K4b: combine 8 m-split partials + normalize ----------------
__global__ __launch_bounds__(256) void k_comb(const bf16* __restrict__ po,
                                              const float* __restrict__ pls,
                                              bf16* __restrict__ gout) {
  int idx = blockIdx.x * 256 + threadIdx.x;        // 524288 chunks of 8 bf16
  int row = idx >> 5;
  const int R = B_ * N_;
  float d = 0.f;
#pragma unroll
  for (int s = 0; s < 8; s++) d += pls[s * R + row];
  float inv = 1.0f / d;
  const size_t S = (size_t)B_ * N_ * D_ / 8;       // uint4 per slab
  const uint4* p = (const uint4*)po;
  float ax = 0, bx = 0, ay = 0, by = 0, az = 0, bz = 0, aw = 0, bw = 0;
#pragma unroll
  for (int s = 0; s < 8; s++) {
    uint4 v = p[idx + s * S];
    ax += lo16(v.x); bx += hi16(v.x);
    ay += lo16(v.y); by += hi16(v.y);
    az += lo16(v.z); bz += hi16(v.z);
    aw += lo16(v.w); bw += hi16(v.w);
  }
  uint4 o;
  o.x = pack2(ax * inv, bx * inv);
  o.y = pack2(ay * inv, by * inv);
  o.z = pack2(az * inv, bz * inv);
  o.w = pack2(aw * inv, bw * inv);
  reinterpret_cast<uint4*>(gout)[idx] = o;
}

// ---------------- K5: fused GRU cell (f32 out) ----------------
__global__ __launch_bounds__(256) void k_gru(const bf16* __restrict__ gout,
                                             const bf16* __restrict__ x16,
                                             const bf16* __restrict__ Wih,
                                             const bf16* __restrict__ Whh,
                                             const float* __restrict__ bih,
                                             const float* __restrict__ bhh,
                                             const float* __restrict__ x32,
                                             float* __restrict__ out) {
  int wid = blockIdx.x * 4 + (threadIdx.x >> 6);   // 4096 waves
  int lane = threadIdx.x & 63, lr = lane & 15, quad = lane >> 4;
  int rs = wid >> 4;                               // 256 row-strips of 64
  int col0 = (wid & 15) << 4;                      // 16 col-tiles
  int row0 = rs << 6;
  int col = col0 + lr;

  float bi[3], bh[3];
#pragma unroll
  for (int g = 0; g < 3; g++) {
    bi[g] = bih[g * 256 + col];
    bh[g] = bhh[g * 256 + col];
  }
  v4f aI[3][4], aH[3][4];
#pragma unroll
  for (int g = 0; g < 3; g++)
#pragma unroll
    for (int rt = 0; rt < 4; rt++) {
      aI[g][rt] = (v4f){0, 0, 0, 0};
      aH[g][rt] = (v4f){0, 0, 0, 0};
    }

#pragma unroll 4
  for (int ks = 0; ks < 8; ks++) {
    int k0 = ks * 32 + quad * 8;
    v8s wI[3], wH[3];
#pragma unroll
    for (int g = 0; g < 3; g++) {
      wI[g] = ldb8(Wih + (size_t)(g * 256 + col0 + lr) * 256 + k0);
      wH[g] = ldb8(Whh + (size_t)(g * 256 + col0 + lr) * 256 + k0);
    }
#pragma unroll
    for (int rt = 0; rt < 4; rt++) {
      v8s aG = ldb8(gout + (size_t)(row0 + rt * 16 + lr) * 256 + k0);
      v8s aX = ldb8(x16 + (size_t)(row0 + rt * 16 + lr) * 256 + k0);
#pragma unroll
      for (int g = 0; g < 3; g++) {
        aI[g][rt] = mfma16(aG, wI[g], aI[g][rt]);
        aH[g][rt] = mfma16(aX, wH[g], aH[g][rt]);
      }
    }
  }

#pragma unroll
  for (int rt = 0; rt < 4; rt++) {
    int rowb = row0 + rt * 16 + quad * 4;
#pragma unroll
    for (int r = 0; r < 4; r++) {
      float ir  = aI[0][rt][r] + bi[0];
      float iz  = aI[1][rt][r] + bi[1];
      float in_ = aI[2][rt][r] + bi[2];
      float hr  = aH[0][rt][r] + bh[0];
      float hz  = aH[1][rt][r] + bh[1];
      float hn  = aH[2][rt][r] + bh[2];
      float rg = fsigmoid(ir + hr);
      float zg = fsigmoid(iz + hz);
      float ng = ftanh(in_ + rg * hn);
      float hv = x32[(size_t)(rowb + r) * 256 + col];
      out[(size_t)(rowb + r) * 256 + col] = (1.0f - zg) * ng + zg * hv;
    }
  }
}

extern "C" void kernel_launch(void* const* d_in, const int* in_sizes, int n_in,
                              void* d_out, int out_size, void* d_ws, size_t ws_size,
                              hipStream_t stream) {
  const int*   adj = (const int*)d_in[0];
  const float* x   = (const float*)d_in[1];
  const float* xt  = (const float*)d_in[2];
  const float* W   = (const float*)d_in[3];
  const float* Wih = (const float*)d_in[4];
  const float* Whh = (const float*)d_in[5];
  const float* bih = (const float*)d_in[6];
  const float* bhh = (const float*)d_in[7];
  float* out = (float*)d_out;

  char* ws = (char*)d_ws;
  bf16*  xb16   = (bf16*)(ws);                               //  8 MiB
  bf16*  xtn    = (bf16*)(ws + (8u << 20));                  //  8 MiB (normalized)
  bf16*  gob    = (bf16*)(ws + (16u << 20));                 //  8 MiB
  bf16*  WhT    = (bf16*)(ws + (24u << 20));                 //  8 MiB
  bf16*  Wt     = (bf16*)(ws + (32u << 20));                 // 128 KiB
  bf16*  Wih16  = (bf16*)(ws + (32u << 20) + (128u << 10));  // 384 KiB
  bf16*  Whh16  = (bf16*)(ws + (32u << 20) + (512u << 10));  // 384 KiB
  float* pls    = (float*)(ws + (32u << 20) + (896u << 10)); // 512 KiB
  u32*   maskT  = (u32*)  (ws + (36u << 20));                //   4 MiB
  bf16*  po     = (bf16*) (ws + (40u << 20));                //  64 MiB (8 slabs)

  k_packT<<<1024, 256, 0, stream>>>(adj, maskT);
  k_cast<<<8192, 256, 0, stream>>>(x, xb16, xt, xtn);
  k_prep<<<640, 256, 0, stream>>>(W, Wt, Wih, Wih16, Whh, Whh16);
  k_wht<<<1024, 256, 0, stream>>>(xb16, Wt, WhT);
  k_attn<<<1024, 256, 0, stream>>>(xtn, maskT, WhT, po, pls);
  k_comb<<<2048, 256, 0, stream>>>(po, pls, gob);
  k_gru<<<1024, 256, 0, stream>>>(gob, xb16, Wih16, Whh16, bih, bhh, x, out);
}

// Round 8
// 392.808 us; speedup vs baseline: 1.4146x; 1.4146x over previous
//
#include <hip/hip_runtime.h>
#include <hip/hip_bf16.h>

#define B_ 8
#define N_ 2048
#define D_ 256

using bf16 = __hip_bfloat16;
typedef short v8s __attribute__((ext_vector_type(8)));
typedef float v4f __attribute__((ext_vector_type(4)));
typedef float v16f __attribute__((ext_vector_type(16)));
typedef unsigned int u32;

__device__ __forceinline__ v4f mfma16(v8s a, v8s b, v4f c) {
  return __builtin_amdgcn_mfma_f32_16x16x32_bf16(a, b, c, 0, 0, 0);
}
__device__ __forceinline__ v16f mfma32(v8s a, v8s b, v16f c) {
  return __builtin_amdgcn_mfma_f32_32x32x16_bf16(a, b, c, 0, 0, 0);
}
__device__ __forceinline__ v8s ldb8(const bf16* p) {
  return *reinterpret_cast<const v8s*>(p);
}
__device__ __forceinline__ void glds16(const void* g, void* l) {
  __builtin_amdgcn_global_load_lds((const __attribute__((address_space(1))) u32*)g,
                                   (__attribute__((address_space(3))) u32*)l, 16, 0, 0);
}
__device__ __forceinline__ unsigned short f2bu(float f) {
  bf16 b = __float2bfloat16(f);
  return *reinterpret_cast<unsigned short*>(&b);
}
__device__ __forceinline__ float bs2f(short s) {
  union { u32 i; float f; } v; v.i = ((u32)(unsigned short)s) << 16; return v.f;
}
__device__ __forceinline__ float lo16(u32 u) { union {u32 i; float f;} v; v.i = u << 16; return v.f; }
__device__ __forceinline__ float hi16(u32 u) { union {u32 i; float f;} v; v.i = u & 0xffff0000u; return v.f; }
__device__ __forceinline__ u32 pack2(float a, float b) {
  return (u32)f2bu(a) | ((u32)f2bu(b) << 16);
}
__device__ __forceinline__ float fsigmoid(float x) { return 1.0f / (1.0f + __expf(-x)); }
__device__ __forceinline__ float ftanh(float x) {
  float ax = fabsf(x);
  float t = __expf(-2.0f * ax);
  float r = (1.0f - t) / (1.0f + t);
  return copysignf(r, x);
}

// ---- K0: fused prep. blocks [0,1024): adj bit-transpose; [1024,9216): x cast /
// xt normalize+cast; [9216,9856): W transpose + Wih/Whh casts. All independent.
__global__ __launch_bounds__(256) void k_pre(const int* __restrict__ adj,
                                             u32* __restrict__ maskT,
                                             const float* __restrict__ x,
                                             bf16* __restrict__ xb16,
                                             const float* __restrict__ xt,
                                             bf16* __restrict__ xtn,
                                             const float* __restrict__ W,
                                             bf16* __restrict__ Wt,
                                             const float* __restrict__ Wih,
                                             bf16* __restrict__ Wih16,
                                             const float* __restrict__ Whh,
                                             bf16* __restrict__ Whh16) {
  int blk = blockIdx.x;
  if (blk < 1024) {
    // bit-transposed mask: maskT[b][g32][col] bit r = adj[row g*32+r][col] > 0
    int bg = blk >> 1, half = blk & 1;
    const int* base = adj + (size_t)bg * 32 * 2048;
    int c0 = half * 1024 + threadIdx.x * 4;
    u32 w0 = 0, w1 = 0, w2 = 0, w3 = 0;
#pragma unroll 4
    for (int r = 0; r < 32; r++) {
      int4 v = *reinterpret_cast<const int4*>(base + r * 2048 + c0);
      w0 |= (u32)(v.x > 0) << r;
      w1 |= (u32)(v.y > 0) << r;
      w2 |= (u32)(v.z > 0) << r;
      w3 |= (u32)(v.w > 0) << r;
    }
    uint4 o; o.x = w0; o.y = w1; o.z = w2; o.w = w3;
    *reinterpret_cast<uint4*>(maskT + (size_t)bg * 2048 + c0) = o;
  } else if (blk < 5120) {
    // x f32 -> bf16
    int i = (blk - 1024) * 256 + threadIdx.x;
    float4 v = reinterpret_cast<const float4*>(x)[i];
    ushort4 o;
    o.x = f2bu(v.x); o.y = f2bu(v.y); o.z = f2bu(v.z); o.w = f2bu(v.w);
    reinterpret_cast<ushort4*>(xb16)[i] = o;
  } else if (blk < 9216) {
    // x_topic: normalize row (one wave per 256-elem row) + cast
    int i = (blk - 5120) * 256 + threadIdx.x;
    float4 v = reinterpret_cast<const float4*>(xt)[i];
    float s = v.x * v.x + v.y * v.y + v.z * v.z + v.w * v.w;
#pragma unroll
    for (int off = 32; off > 0; off >>= 1) s += __shfl_xor(s, off);
    float rinv = 1.0f / fmaxf(sqrtf(s), 1e-8f);
    ushort4 o;
    o.x = f2bu(v.x * rinv); o.y = f2bu(v.y * rinv);
    o.z = f2bu(v.z * rinv); o.w = f2bu(v.w * rinv);
    reinterpret_cast<ushort4*>(xtn)[i] = o;
  } else if (blk < 9472) {
    // W[d][h] -> Wt[h][d]
    int idx = (blk - 9216) * 256 + threadIdx.x;
    int d = idx >> 8, h = idx & 255;
    Wt[h * 256 + d] = __float2bfloat16(W[idx]);
  } else if (blk < 9664) {
    int i = (blk - 9472) * 256 + threadIdx.x;
    float4 v = reinterpret_cast<const float4*>(Wih)[i];
    ushort4 o;
    o.x = f2bu(v.x); o.y = f2bu(v.y); o.z = f2bu(v.z); o.w = f2bu(v.w);
    reinterpret_cast<ushort4*>(Wih16)[i] = o;
  } else {
    int i = (blk - 9664) * 256 + threadIdx.x;
    float4 v = reinterpret_cast<const float4*>(Whh)[i];
    ushort4 o;
    o.x = f2bu(v.x); o.y = f2bu(v.y); o.z = f2bu(v.z); o.w = f2bu(v.w);
    reinterpret_cast<ushort4*>(Whh16)[i] = o;
  }
}

// ---------------- K3: WhT[b][h][m] = sum_d Wt[h][d] * x16[b][m][d] ----------------
__global__ __launch_bounds__(256) void k_wht(const bf16* __restrict__ x,
                                             const bf16* __restrict__ Wt,
                                             bf16* __restrict__ WhT) {
  int wid = blockIdx.x * 4 + (threadIdx.x >> 6);   // 4096 waves
  int lane = threadIdx.x & 63, lr = lane & 15, quad = lane >> 4;
  int b = wid >> 9;
  int rem = wid & 511;
  int h0 = (rem >> 5) << 4;                        // 16 h-tiles
  int m0 = (rem & 31) << 6;                        // 32 m-strips of 64

  v8s a[8];
  const bf16* arow = Wt + (size_t)(h0 + lr) * D_ + quad * 8;
#pragma unroll
  for (int ks = 0; ks < 8; ks++) a[ks] = ldb8(arow + ks * 32);

  const bf16* xb = x + (size_t)b * N_ * D_;
#pragma unroll
  for (int mt = 0; mt < 4; mt++) {
    v4f acc = {0.f, 0.f, 0.f, 0.f};
    const bf16* brow = xb + (size_t)(m0 + mt * 16 + lr) * D_ + quad * 8;
#pragma unroll
    for (int ks = 0; ks < 8; ks++) acc = mfma16(a[ks], ldb8(brow + ks * 32), acc);
    bf16* o = WhT + ((size_t)b * D_ + h0 + quad * 4) * N_ + m0 + mt * 16 + lr;
#pragma unroll
    for (int r = 0; r < 4; r++) o[(size_t)r * N_] = __float2bfloat16(acc[r]);
  }
}

// ---------------- K4: fused attention (round-6 config: dbuf, 512 blocks) -----
// block = 128 Q-rows (wave owns 32), m-split x4. Pre-normalized xtn: QK = cos.
// Mask via bit-transposed maskT: one u32/lane/iter. Double-buffered LDS stage,
// one barrier per iter; 2 blocks/CU keeps blockIdx&7 == batch == XCD-resident.
__global__ __launch_bounds__(256, 2) void k_attn(const bf16* __restrict__ xtn,
                                                 const u32* __restrict__ maskT,
                                                 const bf16* __restrict__ WhT,
                                                 bf16* __restrict__ po,
                                                 float* __restrict__ pls) {
  __shared__ __align__(16) bf16 xts[2][32 * 256];  // 16 KB x2, slot = g ^ (m&7)
  __shared__ __align__(16) bf16 whs[2][256 * 32];  // 16 KB x2, slot = g ^ ((h>>1)&3)
  __shared__ __align__(16) bf16 pbuf[4][32 * 40];  // pitch 80 B, 10 KB

  const int tid = threadIdx.x;
  const int w = tid >> 6, lane = tid & 63;
  const int l5 = lane >> 5, l31 = lane & 31;
  const int b = blockIdx.x & 7;                    // XCD-resident batch
  const int nt = (blockIdx.x >> 3) & 15;
  const int mh = blockIdx.x >> 7;                  // 4 m-splits of 512
  const int n0w = nt * 128 + w * 32;
  const int mbase = mh * 512;

  const bf16* xtb = xtn + (size_t)b * N_ * D_;
  const bf16* whb = WhT + (size_t)b * D_ * N_;

  // Q fragments: A-layout for 32x32x16 (row = l31, k = kt*16 + l5*8 + j)
  v8s q[16];
  {
    const bf16* qrow = xtb + (size_t)(n0w + l31) * D_ + l5 * 8;
#pragma unroll
    for (int kt = 0; kt < 16; kt++) q[kt] = ldb8(qrow + kt * 16);
  }
  // per-lane mask column pointer: bit r = Q-row n0w + r, col = mbase + ii*32 + l31
  const u32* mrow = maskT + ((size_t)(b * 64 + nt * 4 + w)) * 2048 + mbase + l31;

  auto stage = [&](int d, int m0) {
    const char* gx = (const char*)(xtb + (size_t)m0 * D_);
    char* lx = ((char*)xts[d]) + w * 4096;
#pragma unroll
    for (int j = 0; j < 4; j++) {
      int m = w * 8 + j * 2 + l5;
      int gg = l31 ^ (m & 7);
      glds16(gx + (size_t)m * 512 + gg * 16, lx + j * 1024);
    }
    char* lw = ((char*)whs[d]) + w * 4096;
#pragma unroll
    for (int j = 0; j < 4; j++) {
      int h = w * 64 + j * 16 + (lane >> 2);
      int g = (lane & 3) ^ ((lane >> 3) & 3);      // slot = g ^ ((h>>1)&3)
      glds16((const char*)(whb + (size_t)h * N_ + m0) + g * 16, lw + j * 1024);
    }
  };

  v16f o[8];
#pragma unroll
  for (int t = 0; t < 8; t++) o[t] = (v16f)(0.f);
  float lsum = 0.f;

  u32 mword = mrow[0];
  stage(0, mbase);

#pragma unroll 1
  for (int ii = 0; ii < 16; ii++) {
    const int d = ii & 1;
    __syncthreads();                       // drains stage issued last iter
    if (ii + 1 < 16) stage(1 - d, mbase + (ii + 1) * 32);
    u32 mnext = (ii + 1 < 16) ? mrow[(ii + 1) * 32] : 0u;

    // QK: S(32q x 32m) = cos; K-frags from swizzled LDS
    v16f s = (v16f)(0.f);
    const bf16* xb = xts[d] + l31 * 256;
#pragma unroll
    for (int kt = 0; kt < 16; kt++) {
      int g = ((kt * 2 + l5) ^ (l31 & 7)) * 8;
      s = mfma32(q[kt], ldb8(xb + g), s);
    }

    // exp + P staging (C-layout -> pbuf rows); bit per C-row from mword
    bf16* pb = pbuf[w];
#pragma unroll
    for (int j = 0; j < 16; j++) {
      int row = (j & 3) + 8 * (j >> 2) + 4 * l5;
      float p = ((mword >> row) & 1u) ? __expf(s[j]) : 0.f;
      pb[row * 40 + l31] = __float2bfloat16(p);
    }
    mword = mnext;

    // P A-fragments (conflict-free, pitch 80B) + row-sum from the same frags
    v8s pa0 = ldb8(pb + l31 * 40 + l5 * 8);
    v8s pa1 = ldb8(pb + l31 * 40 + 16 + l5 * 8);
#pragma unroll
    for (int e = 0; e < 8; e++) lsum += bs2f(pa0[e]) + bs2f(pa1[e]);

    // PV: O(32q x 256h) += P(32x32) @ Wh(32x256)
#pragma unroll
    for (int ht = 0; ht < 8; ht++) {
      const bf16* wb = whs[d] + (ht * 32 + l31) * 32;
      int s0 = (l5 ^ ((l31 >> 1) & 3)) * 8;
      int s1 = ((2 + l5) ^ ((l31 >> 1) & 3)) * 8;
      o[ht] = mfma32(pa0, ldb8(wb + s0), o[ht]);
      o[ht] = mfma32(pa1, ldb8(wb + s1), o[ht]);
    }
  }

  // partial row-sums: combine the two k-halves; lanes 0..31 hold rows 0..31
  lsum += __shfl_xor(lsum, 32);
  if (lane < 32) pls[(size_t)mh * (B_ * N_) + b * N_ + n0w + l31] = lsum;

  // partial O store (C-layout scatter, bf16)
  bf16* pob = po + (size_t)mh * ((size_t)B_ * N_ * D_) + ((size_t)b * N_ + n0w) * D_;
#pragma unroll
  for (int ht = 0; ht < 8; ht++) {
#pragma unroll
    for (int j = 0; j < 16; j++) {
      int row = (j & 3) + 8 * (j >> 2) + 4 * l5;
      pob[(size_t)row * D_ + ht * 32 + l31] = __float2bfloat16(o[ht][j]);
    }
  }
}

// ---------------- K4b: combine 4 m-split partials + normalize ----------------
__global__ __launch_bounds__(256) void k_comb(const bf16* __restrict__ po,
                                              const float* __restrict__ pls,
                                              bf16* __restrict__ gout) {
  int idx = blockIdx.x * 256 + threadIdx.x;        // 524288 chunks of 8 bf16
  int row = idx >> 5;
  const int R = B_ * N_;
  float inv = 1.0f / (pls[row] + pls[R + row] + pls[2 * R + row] + pls[3 * R + row]);
  const size_t S = (size_t)B_ * N_ * D_ / 8;       // uint4 per slab
  const uint4* p = (const uint4*)po;
  uint4 a = p[idx], c = p[idx + S], e = p[idx + 2 * S], f = p[idx + 3 * S];
  uint4 o;
  o.x = pack2((lo16(a.x)+lo16(c.x)+lo16(e.x)+lo16(f.x)) * inv,
              (hi16(a.x)+hi16(c.x)+hi16(e.x)+hi16(f.x)) * inv);
  o.y = pack2((lo16(a.y)+lo16(c.y)+lo16(e.y)+lo16(f.y)) * inv,
              (hi16(a.y)+hi16(c.y)+hi16(e.y)+hi16(f.y)) * inv);
  o.z = pack2((lo16(a.z)+lo16(c.z)+lo16(e.z)+lo16(f.z)) * inv,
              (hi16(a.z)+hi16(c.z)+hi16(e.z)+hi16(f.z)) * inv);
  o.w = pack2((lo16(a.w)+lo16(c.w)+lo16(e.w)+lo16(f.w)) * inv,
              (hi16(a.w)+hi16(c.w)+hi16(e.w)+hi16(f.w)) * inv);
  reinterpret_cast<uint4*>(gout)[idx] = o;
}

// ---------------- K5: fused GRU cell (f32 out) ----------------
__global__ __launch_bounds__(256) void k_gru(const bf16* __restrict__ gout,
                                             const bf16* __restrict__ x16,
                                             const bf16* __restrict__ Wih,
                                             const bf16* __restrict__ Whh,
                                             const float* __restrict__ bih,
                                             const float* __restrict__ bhh,
                                             const float* __restrict__ x32,
                                             float* __restrict__ out) {
  int wid = blockIdx.x * 4 + (threadIdx.x >> 6);   // 4096 waves
  int lane = threadIdx.x & 63, lr = lane & 15, quad = lane >> 4;
  int rs = wid >> 4;                               // 256 row-strips of 64
  int col0 = (wid & 15) << 4;                      // 16 col-tiles
  int row0 = rs << 6;
  int col = col0 + lr;

  float bi[3], bh[3];
#pragma unroll
  for (int g = 0; g < 3; g++) {
    bi[g] = bih[g * 256 + col];
    bh[g] = bhh[g * 256 + col];
  }
  v4f aI[3][4], aH[3][4];
#pragma unroll
  for (int g = 0; g < 3; g++)
#pragma unroll
    for (int rt = 0; rt < 4; rt++) {
      aI[g][rt] = (v4f){0, 0, 0, 0};
      aH[g][rt] = (v4f){0, 0, 0, 0};
    }

#pragma unroll 4
  for (int ks = 0; ks < 8; ks++) {
    int k0 = ks * 32 + quad * 8;
    v8s wI[3], wH[3];
#pragma unroll
    for (int g = 0; g < 3; g++) {
      wI[g] = ldb8(Wih + (size_t)(g * 256 + col0 + lr) * 256 + k0);
      wH[g] = ldb8(Whh + (size_t)(g * 256 + col0 + lr) * 256 + k0);
    }
#pragma unroll
    for (int rt = 0; rt < 4; rt++) {
      v8s aG = ldb8(gout + (size_t)(row0 + rt * 16 + lr) * 256 + k0);
      v8s aX = ldb8(x16 + (size_t)(row0 + rt * 16 + lr) * 256 + k0);
#pragma unroll
      for (int g = 0; g < 3; g++) {
        aI[g][rt] = mfma16(aG, wI[g], aI[g][rt]);
        aH[g][rt] = mfma16(aX, wH[g], aH[g][rt]);
      }
    }
  }

#pragma unroll
  for (int rt = 0; rt < 4; rt++) {
    int rowb = row0 + rt * 16 + quad * 4;
#pragma unroll
    for (int r = 0; r < 4; r++) {
      float ir  = aI[0][rt][r] + bi[0];
      float iz  = aI[1][rt][r] + bi[1];
      float in_ = aI[2][rt][r] + bi[2];
      float hr  = aH[0][rt][r] + bh[0];
      float hz  = aH[1][rt][r] + bh[1];
      float hn  = aH[2][rt][r] + bh[2];
      float rg = fsigmoid(ir + hr);
      float zg = fsigmoid(iz + hz);
      float ng = ftanh(in_ + rg * hn);
      float hv = x32[(size_t)(rowb + r) * 256 + col];
      out[(size_t)(rowb + r) * 256 + col] = (1.0f - zg) * ng + zg * hv;
    }
  }
}

extern "C" void kernel_launch(void* const* d_in, const int* in_sizes, int n_in,
                              void* d_out, int out_size, void* d_ws, size_t ws_size,
                              hipStream_t stream) {
  const int*   adj = (const int*)d_in[0];
  const float* x   = (const float*)d_in[1];
  const float* xt  = (const float*)d_in[2];
  const float* W   = (const float*)d_in[3];
  const float* Wih = (const float*)d_in[4];
  const float* Whh = (const float*)d_in[5];
  const float* bih = (const float*)d_in[6];
  const float* bhh = (const float*)d_in[7];
  float* out = (float*)d_out;

  char* ws = (char*)d_ws;
  bf16*  xb16   = (bf16*)(ws);                               //  8 MiB
  bf16*  xtn    = (bf16*)(ws + (8u << 20));                  //  8 MiB (normalized)
  bf16*  gob    = (bf16*)(ws + (16u << 20));                 //  8 MiB
  bf16*  WhT    = (bf16*)(ws + (24u << 20));                 //  8 MiB
  bf16*  Wt     = (bf16*)(ws + (32u << 20));                 // 128 KiB
  bf16*  Wih16  = (bf16*)(ws + (32u << 20) + (128u << 10));  // 384 KiB
  bf16*  Whh16  = (bf16*)(ws + (32u << 20) + (512u << 10));  // 384 KiB
  u32*   maskT  = (u32*)  (ws + (32u << 20) + (960u << 10)); //   4 MiB
  bf16*  po     = (bf16*) (ws + (40u << 20));                //  32 MiB (4 slabs)
  float* pls    = (float*)(ws + (72u << 20));                // 256 KiB

  k_pre<<<9856, 256, 0, stream>>>(adj, maskT, x, xb16, xt, xtn,
                                  W, Wt, Wih, Wih16, Whh, Whh16);
  k_wht<<<1024, 256, 0, stream>>>(xb16, Wt, WhT);
  k_attn<<<512, 256, 0, stream>>>(xtn, maskT, WhT, po, pls);
  k_comb<<<2048, 256, 0, stream>>>(po, pls, gob);
  k_gru<<<1024, 256, 0, stream>>>(gob, xb16, Wih16, Whh16, bih, bhh, x, out);
}